// Round 18
// baseline (47.067 us; speedup 1.0000x reference)
//
#include <hip/hip_runtime.h>

typedef unsigned short u16;
typedef __attribute__((ext_vector_type(8))) __bf16 bf16x8;
typedef __attribute__((ext_vector_type(4))) float f32x4;

static __device__ __forceinline__ u16 f2bf(float f) {
  unsigned int u = __float_as_uint(f);
  u += 0x7fffu + ((u >> 16) & 1u);   // round-to-nearest-even
  return (u16)(u >> 16);
}

// Problem constants
#define BATCH 32
#define NN 1024
#define MM 512

// X-side chunk swizzle (R10/R15-proven at b128): per-8-row bijective.
static __device__ __forceinline__ int swz(int r) { return ((r >> 1) ^ ((r & 1) << 2)) & 7; }

// ---- kernel 1: FRAGMENT-MAJOR E|O matrix ----
// G3 index = ((((((jt*4+wm)*8+s)*2+ks)*2+eo)*2+mf)*64+lane)*8+sub   (u16, 1 MiB)
// j = jt*128 + wm*32 + mf*16 + (lane&15); p = s*64 + (ks*4+(lane>>4))*8 + sub;
// k = 2p + eo;  value = M[j][k] = (k==0 ? 1/32 : sqrt(2/1024)*cos(pi*k*(2j+1)/2048)).
// Each (jt,wm,s,ks,eo,mf) fragment is 1KB contiguous -> ONE coalesced b128 load/wave.
__global__ void fill_g(u16* __restrict__ G) {
  int idx = blockIdx.x * 256 + threadIdx.x;  // 524288
  int sub  = idx & 7;
  int lane = (idx >> 3) & 63;
  int mf   = (idx >> 9) & 1;
  int eo   = (idx >> 10) & 1;
  int ks   = (idx >> 11) & 1;
  int s    = (idx >> 12) & 7;
  int wm   = (idx >> 15) & 3;
  int jt   = (idx >> 17) & 3;
  int j = jt * 128 + wm * 32 + mf * 16 + (lane & 15);
  int p = s * 64 + (ks * 4 + (lane >> 4)) * 8 + sub;
  int k = 2 * p + eo;
  float v;
  if (k == 0) {
    v = 0.03125f;  // 1/sqrt(1024)
  } else {
    int ph = (k * (2 * j + 1)) & 4095;
    v = 0.04419417382415922f * cosf((float)ph * 1.5339807878856412e-3f);
  }
  G[idx] = f2bf(v);
}

// ---- kernel 2: fused folded GEMM, A-direct (no LDS for A) ----
// out[j] = (E.Xe + O.Xo)[j], out[1023-j] = (E.Xe - O.Xo)[j].
// Block 512 thr / 8 waves (4wm x 2wn), tile 128jh x 64c; wave 32jh x 32c (E+O).
// LDS: sX[64 c][128 u16] = 16 KiB ONLY. A-fragments load straight from G3
// (fragment-major, coalesced 1KB per instr, L2-resident) into MFMA operand regs
// -> no gload_lds, no A barriers, no hand vmcnt anywhere.
// Step s (128 k): WRITE_X(s) [2 ds_write_b128, auto reg-wait]; lgkm(0); b1;
//   LOAD_X(s+1) [16 dword globals]; A-frag loads ks0+ks1 [8 x 1KB b128 globals];
//   per ks: 4 X-frag ds_reads + 8 MFMA (compiler waits per-use); b2 (bare).
// Regs ~108: acc 32 + A 32 + xr 16 + Xfrag 16 + addr -> (512,4): 4 waves/SIMD.
__global__ __launch_bounds__(512, 4) void gemm_idct(const u16* __restrict__ G,
                                                    const float* __restrict__ X,
                                                    float* __restrict__ C) {
  __shared__ __align__(16) u16 sX[8192];  // [64 c][128] (E chunks 0-7 | O 64+)
  // --- XCD decode: 4 jt-sharers of each (ct,b) X-panel share wg&7 ---
  const int wg    = blockIdx.x;
  const int xcd   = wg & 7;
  const int local = wg >> 3;                  // 0..127
  const int jt    = local & 3;                // jh tile (128 rows)
  const int pg    = xcd * 32 + (local >> 2);  // 0..255
  const int ct    = pg & 7;                   // c tile (64 cols)
  const int b     = pg >> 3;                  // batch

  const int t = threadIdx.x;
  const int wave = t >> 6, lane = t & 63;
  const int wm = wave >> 1, wn = wave & 1;    // 4 x 2 waves
  const int lhi = lane >> 4, llo = lane & 15;

  // --- A-fragment source: per (s,ks,eo,mf) 1KB blocks, lane-linear ---
  const u16* gAF = G + (size_t)(jt * 4 + wm) * 32768 + lane * 8;
  // offset(s,ks,eo,mf) = s*4096 + ((ks*2+eo)*2+mf)*512   (u16)

  // --- X staging: lane owns c = t&63, k-16th kw = t>>6 (16 k per step) ---
  const int cx = t & 63;
  const int kw = t >> 6;  // 0..7
  const float* gX = X + ((size_t)b * NN + kw * 16) * MM + ct * 64 + cx;

  float xr[16];
#define LOAD_X(s)                                                              \
  do {                                                                         \
    const float* p = gX + (size_t)(s) * 128 * MM;                              \
    _Pragma("unroll") for (int i = 0; i < 16; ++i)                             \
      xr[i] = p[(size_t)i * MM];                                               \
  } while (0)

  // k = kw*16 + 2i + eo -> p-local = kw*8 + i -> chunk kw, sub i.
#define WRITE_X()                                                              \
  do {                                                                         \
    const int f = swz(cx);                                                     \
    bf16x8 e, o;                                                               \
    _Pragma("unroll") for (int i = 0; i < 8; ++i) {                            \
      e[i] = (__bf16)xr[2 * i];                                                \
      o[i] = (__bf16)xr[2 * i + 1];                                            \
    }                                                                          \
    const int ch = kw ^ f;                                                     \
    *(bf16x8*)&sX[cx * 128 + ch * 8] = e;                                      \
    *(bf16x8*)&sX[cx * 128 + 64 + ch * 8] = o;                                 \
  } while (0)

  f32x4 accE[2][2] = {};
  f32x4 accO[2][2] = {};

#define STEP(s)                                                                \
  do {                                                                         \
    WRITE_X(); /* auto reg-wait on xr */                                       \
    asm volatile("s_waitcnt lgkmcnt(0)" ::: "memory");                         \
    __builtin_amdgcn_sched_barrier(0);                                         \
    __builtin_amdgcn_s_barrier(); /* b1: sX(s) visible */                      \
    __builtin_amdgcn_sched_barrier(0);                                         \
    if ((s) < 7) LOAD_X((s) + 1);                                              \
    bf16x8 fe[2][2], fo[2][2];  /* [ks][mf] */                                 \
    _Pragma("unroll") for (int ks = 0; ks < 2; ++ks)                           \
      _Pragma("unroll") for (int mf = 0; mf < 2; ++mf) {                       \
        fe[ks][mf] = *(const bf16x8*)(gAF + (s) * 4096 + ((ks * 2 + 0) * 2 + mf) * 512); \
        fo[ks][mf] = *(const bf16x8*)(gAF + (s) * 4096 + ((ks * 2 + 1) * 2 + mf) * 512); \
      }                                                                        \
    _Pragma("unroll") for (int ks = 0; ks < 2; ++ks) {                         \
      bf16x8 fxe[2], fxo[2];                                                   \
      _Pragma("unroll") for (int nf = 0; nf < 2; ++nf) {                       \
        const int rb = wn * 32 + nf * 16 + llo;                                \
        const int cb = ((ks * 4 + lhi) ^ swz(rb)) << 3;                        \
        fxe[nf] = *(const bf16x8*)&sX[rb * 128 + cb];                          \
        fxo[nf] = *(const bf16x8*)&sX[rb * 128 + 64 + cb];                     \
      }                                                                        \
      __builtin_amdgcn_s_setprio(1);                                           \
      _Pragma("unroll") for (int mf = 0; mf < 2; ++mf)                         \
        _Pragma("unroll") for (int nf = 0; nf < 2; ++nf)                       \
          accE[mf][nf] = __builtin_amdgcn_mfma_f32_16x16x32_bf16(              \
              fe[ks][mf], fxe[nf], accE[mf][nf], 0, 0, 0);                     \
      _Pragma("unroll") for (int mf = 0; mf < 2; ++mf)                         \
        _Pragma("unroll") for (int nf = 0; nf < 2; ++nf)                       \
          accO[mf][nf] = __builtin_amdgcn_mfma_f32_16x16x32_bf16(              \
              fo[ks][mf], fxo[nf], accO[mf][nf], 0, 0, 0);                     \
      __builtin_amdgcn_s_setprio(0);                                           \
    }                                                                          \
    __builtin_amdgcn_sched_barrier(0);                                         \
    __builtin_amdgcn_s_barrier(); /* b2: reads(s) precede WRITE_X(s+1) */      \
    __builtin_amdgcn_sched_barrier(0);                                         \
  } while (0)

  // ---- prologue ----
  LOAD_X(0);

  STEP(0); STEP(1); STEP(2); STEP(3);
  STEP(4); STEP(5); STEP(6); STEP(7);

  // ---- epilogue: out[j] = Ye+Yo, out[1023-j] = Ye-Yo ----
  // C/D layout (m89-verified): col = lane&15, row = (lane>>4)*4 + reg
  float* Cb = C + (size_t)b * NN * MM;
  const int cbase = ct * 64 + wn * 32 + llo;
#pragma unroll
  for (int mf = 0; mf < 2; ++mf)
#pragma unroll
    for (int nf = 0; nf < 2; ++nf) {
      const int jh0 = jt * 128 + wm * 32 + mf * 16 + lhi * 4;
      const int c   = cbase + nf * 16;
#pragma unroll
      for (int r = 0; r < 4; ++r) {
        const float ye = accE[mf][nf][r];
        const float yo = accO[mf][nf][r];
        const int j = jh0 + r;
        Cb[(size_t)j * MM + c]            = ye + yo;
        Cb[(size_t)(NN - 1 - j) * MM + c] = ye - yo;
      }
    }
#undef LOAD_X
#undef WRITE_X
#undef STEP
}

extern "C" void kernel_launch(void* const* d_in, const int* in_sizes, int n_in,
                              void* d_out, int out_size, void* d_ws, size_t ws_size,
                              hipStream_t stream) {
  const float* x = (const float*)d_in[0];
  float* out = (float*)d_out;
  u16* G = (u16*)d_ws;  // 524288 u16 = 1 MiB

  fill_g<<<dim3(2048), dim3(256), 0, stream>>>(G);
  gemm_idct<<<dim3(1024), dim3(512), 0, stream>>>(G, x, out);
}

// Round 19
// 45.919 us; speedup vs baseline: 1.0250x; 1.0250x over previous
//
#include <hip/hip_runtime.h>

typedef unsigned short u16;
typedef __attribute__((ext_vector_type(8))) __bf16 bf16x8;
typedef __attribute__((ext_vector_type(4))) float f32x4;

static __device__ __forceinline__ u16 f2bf(float f) {
  unsigned int u = __float_as_uint(f);
  u += 0x7fffu + ((u >> 16) & 1u);   // round-to-nearest-even
  return (u16)(u >> 16);
}

// Problem constants
#define BATCH 32
#define NN 1024
#define MM 512

// X-side chunk swizzle (R10/R15-proven at b128): per-8 bijective, 2-way beats.
static __device__ __forceinline__ int swz(int r) { return ((r >> 1) ^ ((r & 1) << 2)) & 7; }

// ---- kernel 1 (R18-verbatim): FRAGMENT-MAJOR E|O matrix ----
// G3 index = ((((((jt*4+wm)*8+s)*2+ks)*2+eo)*2+mf)*64+lane)*8+sub   (u16, 1 MiB)
// j = jt*128 + wm*32 + mf*16 + (lane&15); p = s*64 + (ks*4+(lane>>4))*8 + sub;
// k = 2p + eo. Each (jt,wm,s,ks,eo,mf) fragment = 1KB contiguous -> 1 b128/wave.
__global__ void fill_g(u16* __restrict__ G) {
  int idx = blockIdx.x * 256 + threadIdx.x;  // 524288
  int sub  = idx & 7;
  int lane = (idx >> 3) & 63;
  int mf   = (idx >> 9) & 1;
  int eo   = (idx >> 10) & 1;
  int ks   = (idx >> 11) & 1;
  int s    = (idx >> 12) & 7;
  int wm   = (idx >> 15) & 3;
  int jt   = (idx >> 17) & 3;
  int j = jt * 128 + wm * 32 + mf * 16 + (lane & 15);
  int p = s * 64 + (ks * 4 + (lane >> 4)) * 8 + sub;
  int k = 2 * p + eo;
  float v;
  if (k == 0) {
    v = 0.03125f;  // 1/sqrt(1024)
  } else {
    int ph = (k * (2 * j + 1)) & 4095;
    v = 0.04419417382415922f * cosf((float)ph * 1.5339807878856412e-3f);
  }
  G[idx] = f2bf(v);
}

// ---- kernel 2: fused folded GEMM, A-direct + 4-step cadence (BK=256 k) ----
// out[j] = (E.Xe + O.Xo)[j], out[1023-j] = (E.Xe - O.Xo)[j].
// Block 512 thr / 8 waves (4wm x 2wn), tile 128jh x 64c; wave 32jh x 32c (E+O).
// LDS: sX[2 phalf][64 c][128 u16] = 32 KiB single-buffered (each phalf = one
// R18-style sub-tile: E chunks 0-7 | O at +64). A-frags load straight from G3
// into MFMA operand regs (per-use compiler waits; L2-hot). NO vmcnt anywhere.
// Step sp (256 k = 128 p): WRITE_X(sp) [4 ds_write_b128, auto reg-wait on xr
//   loaded a full step earlier]; lgkm(0); b1; if sp<3 LOAD_X(sp+1) [32 dwords];
//   4 p-slices q: {4 A-frag b128 + 4 X-frag ds_read + 16 MFMA}; b2.
// 64 MFMA/wave/step, 8 barriers total (vs 16 in R16).
__global__ __launch_bounds__(512, 4) void gemm_idct(const u16* __restrict__ G,
                                                    const float* __restrict__ X,
                                                    float* __restrict__ C) {
  __shared__ __align__(16) u16 sX[2][64][128];  // [phalf][c][E 0-63|O 64-127]
  // --- XCD decode: 4 jt-sharers of each (ct,b) X-panel share wg&7 ---
  const int wg    = blockIdx.x;
  const int xcd   = wg & 7;
  const int local = wg >> 3;                  // 0..127
  const int jt    = local & 3;                // jh tile (128 rows)
  const int pg    = xcd * 32 + (local >> 2);  // 0..255
  const int ct    = pg & 7;                   // c tile (64 cols)
  const int b     = pg >> 3;                  // batch

  const int t = threadIdx.x;
  const int wave = t >> 6, lane = t & 63;
  const int wm = wave >> 1, wn = wave & 1;    // 4 x 2 waves
  const int lhi = lane >> 4, llo = lane & 15;

  // --- A-fragment source (R18 layout): offset(s,ks,eo,mf) = s*4096+((ks*2+eo)*2+mf)*512
  const u16* gAF = G + (size_t)(jt * 4 + wm) * 32768 + lane * 8;

  // --- X staging: lane owns c = t&63, k-eighth kw = t>>6 (32 k per step) ---
  const int cx = t & 63;
  const int kw = t >> 6;  // 0..7: k-local = kw*32..+32; phalf = kw>>2, kq = kw&3
  const float* gX = X + ((size_t)b * NN + kw * 32) * MM + ct * 64 + cx;

  float xr[32];
#define LOAD_X(sp)                                                             \
  do {                                                                         \
    const float* p = gX + (size_t)(sp) * 256 * MM;                             \
    _Pragma("unroll") for (int i = 0; i < 32; ++i)                             \
      xr[i] = p[(size_t)i * MM];                                               \
  } while (0)

  // k-local = kw*32 + 2m + eo -> p-local-in-step = kw*16 + m; within phalf:
  // chunk = kq*2 + (m>>3), sub = m&7.  E chunk holds xr[2m], O holds xr[2m+1].
#define WRITE_X()                                                              \
  do {                                                                         \
    const int f = swz(cx);                                                     \
    const int ph_ = kw >> 2, kq = kw & 3;                                      \
    _Pragma("unroll") for (int h = 0; h < 2; ++h) {                            \
      bf16x8 e, o;                                                             \
      _Pragma("unroll") for (int i = 0; i < 8; ++i) {                          \
        e[i] = (__bf16)xr[2 * (h * 8 + i)];                                    \
        o[i] = (__bf16)xr[2 * (h * 8 + i) + 1];                                \
      }                                                                        \
      const int ch = (kq * 2 + h) ^ f;                                         \
      *(bf16x8*)&sX[ph_][cx][ch * 8] = e;                                      \
      *(bf16x8*)&sX[ph_][cx][64 + ch * 8] = o;                                 \
    }                                                                          \
  } while (0)

  f32x4 accE[2][2] = {};
  f32x4 accO[2][2] = {};

#define STEP(sp)                                                               \
  do {                                                                         \
    WRITE_X(); /* auto reg-wait on xr (loaded a full step ago) */              \
    asm volatile("s_waitcnt lgkmcnt(0)" ::: "memory");                         \
    __builtin_amdgcn_sched_barrier(0);                                         \
    __builtin_amdgcn_s_barrier(); /* b1: sX(sp) visible */                     \
    __builtin_amdgcn_sched_barrier(0);                                         \
    if ((sp) < 3) LOAD_X((sp) + 1);                                            \
    _Pragma("unroll") for (int q = 0; q < 4; ++q) {                            \
      const int s18 = (sp) * 2 + (q >> 1);                                     \
      const int ks2 = q & 1;                                                   \
      bf16x8 fe[2], fo[2], fxe[2], fxo[2];                                     \
      _Pragma("unroll") for (int mf = 0; mf < 2; ++mf) {                       \
        fe[mf] = *(const bf16x8*)(gAF + s18 * 4096 + ((ks2 * 2 + 0) * 2 + mf) * 512); \
        fo[mf] = *(const bf16x8*)(gAF + s18 * 4096 + ((ks2 * 2 + 1) * 2 + mf) * 512); \
      }                                                                        \
      _Pragma("unroll") for (int nf = 0; nf < 2; ++nf) {                       \
        const int rb = wn * 32 + nf * 16 + llo;                                \
        const int cb = ((ks2 * 4 + lhi) ^ swz(rb)) << 3;                       \
        fxe[nf] = *(const bf16x8*)&sX[q >> 1][rb][cb];                         \
        fxo[nf] = *(const bf16x8*)&sX[q >> 1][rb][64 + cb];                    \
      }                                                                        \
      __builtin_amdgcn_s_setprio(1);                                           \
      _Pragma("unroll") for (int mf = 0; mf < 2; ++mf)                         \
        _Pragma("unroll") for (int nf = 0; nf < 2; ++nf)                       \
          accE[mf][nf] = __builtin_amdgcn_mfma_f32_16x16x32_bf16(              \
              fe[mf], fxe[nf], accE[mf][nf], 0, 0, 0);                         \
      _Pragma("unroll") for (int mf = 0; mf < 2; ++mf)                         \
        _Pragma("unroll") for (int nf = 0; nf < 2; ++nf)                       \
          accO[mf][nf] = __builtin_amdgcn_mfma_f32_16x16x32_bf16(              \
              fo[mf], fxo[nf], accO[mf][nf], 0, 0, 0);                         \
      __builtin_amdgcn_s_setprio(0);                                           \
    }                                                                          \
    __builtin_amdgcn_sched_barrier(0);                                         \
    __builtin_amdgcn_s_barrier(); /* b2: reads(sp) precede WRITE_X(sp+1) */    \
    __builtin_amdgcn_sched_barrier(0);                                         \
  } while (0)

  // ---- prologue ----
  LOAD_X(0);

  STEP(0); STEP(1); STEP(2); STEP(3);

  // ---- epilogue: out[j] = Ye+Yo, out[1023-j] = Ye-Yo ----
  // C/D layout (m89-verified): col = lane&15, row = (lane>>4)*4 + reg
  float* Cb = C + (size_t)b * NN * MM;
  const int cbase = ct * 64 + wn * 32 + llo;
#pragma unroll
  for (int mf = 0; mf < 2; ++mf)
#pragma unroll
    for (int nf = 0; nf < 2; ++nf) {
      const int jh0 = jt * 128 + wm * 32 + mf * 16 + lhi * 4;
      const int c   = cbase + nf * 16;
#pragma unroll
      for (int r = 0; r < 4; ++r) {
        const float ye = accE[mf][nf][r];
        const float yo = accO[mf][nf][r];
        const int j = jh0 + r;
        Cb[(size_t)j * MM + c]            = ye + yo;
        Cb[(size_t)(NN - 1 - j) * MM + c] = ye - yo;
      }
    }
#undef LOAD_X
#undef WRITE_X
#undef STEP
}

extern "C" void kernel_launch(void* const* d_in, const int* in_sizes, int n_in,
                              void* d_out, int out_size, void* d_ws, size_t ws_size,
                              hipStream_t stream) {
  const float* x = (const float*)d_in[0];
  float* out = (float*)d_out;
  u16* G = (u16*)d_ws;  // 524288 u16 = 1 MiB

  fill_g<<<dim3(2048), dim3(256), 0, stream>>>(G);
  gemm_idct<<<dim3(1024), dim3(512), 0, stream>>>(G, x, out);
}